// Round 2
// baseline (78.981 us; speedup 1.0000x reference)
//
#include <hip/hip_runtime.h>
#include <math.h>
#include <limits.h>

#define NCHUNK 16
#define PLACEHOLDER (-1)

typedef float f32x4 __attribute__((ext_vector_type(4)));

// Combine (max, sum-of-exp-relative-to-max, argmax-index) pairs.
// Tie-break: lower index wins (matches jnp.argmax first-occurrence).
__device__ __forceinline__ void comb_ms(float& m, float& s, int& i,
                                        float m2, float s2, int i2) {
  if (m2 > m || (m2 == m && i2 < i)) {
    if (m2 > m) {
      s = (m == -INFINITY ? 0.f : s * expf(m - m2)) + s2;
      m = m2;
    } else {
      s += s2;
    }
    i = i2;
  } else {
    s += (m2 == -INFINITY) ? 0.f : s2 * expf(m2 - m);
  }
}

__device__ __forceinline__ void comb_mx(float& m, int& i, float m2, int i2) {
  if (m2 > m || (m2 == m && i2 < i)) { m = m2; i = i2; }
}

// Pass 1: per-(row, chunk) partial {max logit, sum exp, argmax idx}.
// Normal (caching) loads: logits are re-read by pass 2, let L2/L3 keep them.
__global__ __launch_bounds__(256) void k_stats_partial(
    const float* __restrict__ logits, int V, int chunk_elems,
    float* __restrict__ pm, float* __restrict__ ps, int* __restrict__ pidx) {
  const int row = blockIdx.y;
  const int chunk = blockIdx.x;
  const int tid = threadIdx.x;
  const int begin = chunk * chunk_elems;
  const int end = min(begin + chunk_elems, V);

  float m = -INFINITY, ssum = 0.f;
  int mi = INT_MAX;
  const float* xrow = logits + (size_t)row * V;
  const f32x4* x4 = (const f32x4*)xrow;
  const int vbeg = begin >> 2;
  const int vend = end >> 2;
  for (int i = vbeg + tid; i < vend; i += 256) {
    f32x4 v = x4[i];
    const int gi = i << 2;
#pragma unroll
    for (int k = 0; k < 4; ++k) {
      float x = v[k];
      if (x > m) {
        ssum = ssum * expf(m - x) + 1.f;
        m = x;
        mi = gi + k;
      } else {
        ssum += expf(x - m);
      }
    }
  }
  // scalar tail (only if V % 4 != 0)
  for (int j = (vend << 2) + tid; j < end; j += 256) {
    float x = xrow[j];
    if (x > m) { ssum = ssum * expf(m - x) + 1.f; m = x; mi = j; }
    else       { ssum += expf(x - m); }
  }

  for (int off = 32; off; off >>= 1) {
    float m2 = __shfl_xor(m, off);
    float s2 = __shfl_xor(ssum, off);
    int   i2 = __shfl_xor(mi, off);
    comb_ms(m, ssum, mi, m2, s2, i2);
  }
  __shared__ float lm[4], ls[4];
  __shared__ int li[4];
  const int wv = tid >> 6;
  if ((tid & 63) == 0) { lm[wv] = m; ls[wv] = ssum; li[wv] = mi; }
  __syncthreads();
  if (tid == 0) {
#pragma unroll
    for (int w = 1; w < 4; ++w) comb_ms(m, ssum, mi, lm[w], ls[w], li[w]);
    const int o = row * NCHUNK + chunk;
    pm[o] = m; ps[o] = ssum; pidx[o] = mi;
  }
}

// Pass 2: per-(row, chunk) partial argmax of max(p - q, 0) * inv_q.
// Each block redundantly reduces the row's 16 {M, Z} partials first
// (identical xor-8,4,2,1 tree as k_finalize -> bitwise-identical M, Z).
// Greedy rows (top_k == 1) early-out.
__global__ __launch_bounds__(256) void k_score(
    const float* __restrict__ logits, const float* __restrict__ draft,
    const float* __restrict__ invq, const int* __restrict__ topk,
    const float* __restrict__ pm, const float* __restrict__ ps,
    int V, int S, int chunk_elems,
    float* __restrict__ psm, int* __restrict__ psi) {
  const int row = blockIdx.y;
  const int chunk = blockIdx.x;
  const int tid = threadIdx.x;
  const int b = row / S;
  const int o = row * NCHUNK + chunk;
  if (topk[b] == 1) {
    if (tid == 0) { psm[o] = 0.f; psi[o] = 0; }
    return;
  }

  __shared__ float sM, sInvZ;
  if (tid < 64) {
    float m = -INFINITY, ssum = 0.f;
    int mi = INT_MAX;
    if (tid < NCHUNK) {
      m = pm[row * NCHUNK + tid];
      ssum = ps[row * NCHUNK + tid];
      mi = tid;
    }
    for (int off = 8; off; off >>= 1) {
      float m2 = __shfl_xor(m, off);
      float s2 = __shfl_xor(ssum, off);
      int   i2 = __shfl_xor(mi, off);
      comb_ms(m, ssum, mi, m2, s2, i2);
    }
    if (tid == 0) { sM = m; sInvZ = 1.0f / ssum; }
  }
  __syncthreads();
  const float M = sM;
  const float invZ = sInvZ;

  const int begin = chunk * chunk_elems;
  const int end = min(begin + chunk_elems, V);

  float smx = -INFINITY;
  int si = INT_MAX;
  const float* lrow = logits + (size_t)row * V;
  const float* drow = draft + (size_t)row * V;
  const float* qrow = invq + (size_t)b * V;
  const f32x4* l4 = (const f32x4*)lrow;
  const f32x4* d4 = (const f32x4*)drow;
  const f32x4* q4 = (const f32x4*)qrow;
  const int vbeg = begin >> 2;
  const int vend = end >> 2;
  for (int i = vbeg + tid; i < vend; i += 256) {
    f32x4 lv = __builtin_nontemporal_load(l4 + i);  // last read of logits
    f32x4 dv = __builtin_nontemporal_load(d4 + i);  // only read of draft
    f32x4 qv = q4[i];                               // reused across S rows: cache
    const int gi = i << 2;
#pragma unroll
    for (int k = 0; k < 4; ++k) {
      float p = expf(lv[k] - M) * invZ;
      float sc = fmaxf(p - dv[k], 0.f) * qv[k];
      if (sc > smx) { smx = sc; si = gi + k; }
    }
  }
  // scalar tail (only if V % 4 != 0)
  for (int j = (vend << 2) + tid; j < end; j += 256) {
    float p = expf(lrow[j] - M) * invZ;
    float sc = fmaxf(p - drow[j], 0.f) * qrow[j];
    if (sc > smx) { smx = sc; si = j; }
  }

  for (int off = 32; off; off >>= 1) {
    float m2 = __shfl_xor(smx, off);
    int   i2 = __shfl_xor(si, off);
    comb_mx(smx, si, m2, i2);
  }
  __shared__ float lsm[4];
  __shared__ int lsi[4];
  const int wv = tid >> 6;
  if ((tid & 63) == 0) { lsm[wv] = smx; lsi[wv] = si; }
  __syncthreads();
  if (tid == 0) {
#pragma unroll
    for (int w = 1; w < 4; ++w) comb_mx(smx, si, lsm[w], lsi[w]);
    psm[o] = smx; psi[o] = si;
  }
}

// Finalize: one block per batch row b, 64 lanes = 4 seq-positions x 16 chunks.
// Reduces stats + score partials, computes accept, then the S+1 prefix logic.
__global__ __launch_bounds__(64) void k_finalize(
    const float* __restrict__ logits, const float* __restrict__ draft,
    const int* __restrict__ draft_ids, const int* __restrict__ bonus,
    const int* __restrict__ topk, const float* __restrict__ uniform,
    const float* __restrict__ pm, const float* __restrict__ ps,
    const int* __restrict__ pidx,
    const float* __restrict__ psm, const int* __restrict__ psi,
    int B, int S, int V, int* __restrict__ out) {
  const int b = blockIdx.x;
  const int lane = threadIdx.x;
  const int s = lane >> 4;   // sequence position (requires S <= 4, NCHUNK == 16)
  const int c = lane & 15;   // chunk

  __shared__ int rec[4], tamax[4], acc[4];

  float m = -INFINITY, ssum = 0.f;
  int mi = INT_MAX;
  float sm = -INFINITY;
  int si = INT_MAX;
  if (s < S) {
    const int o = (b * S + s) * NCHUNK + c;
    m = pm[o]; ssum = ps[o]; mi = pidx[o];
    sm = psm[o]; si = psi[o];
  }
  for (int off = 8; off; off >>= 1) {
    float m2 = __shfl_xor(m, off);
    float s2 = __shfl_xor(ssum, off);
    int   i2 = __shfl_xor(mi, off);
    comb_ms(m, ssum, mi, m2, s2, i2);
    float sm2 = __shfl_xor(sm, off);
    int   si2 = __shfl_xor(si, off);
    comb_mx(sm, si, sm2, si2);
  }
  if (c == 0 && s < S) {
    const int row = b * S + s;
    tamax[s] = mi;
    rec[s] = si;
    const int tok = draft_ids[row];
    const float lat = logits[(size_t)row * V + tok];
    const float dat = draft[(size_t)row * V + tok];
    const float tat = expf(lat - m) / ssum;
    const float u = uniform[row];
    const float ratio = (dat > 0.f) ? (tat / dat) : 0.f;
    acc[s] = (dat > 0.f && ratio >= u) ? 1 : 0;
  }
  __syncthreads();

  if (lane == 0) {
    const bool greedy = (topk[b] == 1);
    int tok[9];
    bool rejected_before = false, any_rej = false;
    for (int ss = 0; ss < S; ++ss) {
      const int row = b * S + ss;
      const int dtok = draft_ids[row];
      int t;
      bool rej;
      if (greedy) {
        const int ta = tamax[ss];
        rej = (dtok != ta);
        t = ta;
      } else {
        const int a = acc[ss];
        rej = !a;
        t = a ? dtok : rec[ss];
      }
      tok[ss] = rejected_before ? PLACEHOLDER : t;
      any_rej = any_rej || rej;
      rejected_before = rejected_before || rej;
    }
    tok[S] = any_rej ? PLACEHOLDER : bonus[b];
    int na = 0;
    const int Sp1 = S + 1;
    for (int j = 0; j < Sp1; ++j) na += (tok[j] != PLACEHOLDER);
    for (int j = 0; j < Sp1; ++j) out[b * Sp1 + j] = tok[j];
    out[B * Sp1 + b] = Sp1 - na;             // num_rejected_tokens
    out[B * Sp1 + B + b] = tok[na - 1];      // last_token_ids
  }
}

extern "C" void kernel_launch(void* const* d_in, const int* in_sizes, int n_in,
                              void* d_out, int out_size, void* d_ws, size_t ws_size,
                              hipStream_t stream) {
  const float* logits = (const float*)d_in[0];
  const float* draft  = (const float*)d_in[1];
  const int*   dids   = (const int*)d_in[2];
  const int*   bonus  = (const int*)d_in[3];
  const int*   topk   = (const int*)d_in[4];
  const float* unif   = (const float*)d_in[5];
  const float* invq   = (const float*)d_in[6];
  int* out = (int*)d_out;

  const int B = in_sizes[3];
  const int S = in_sizes[2] / B;
  const int V = in_sizes[0] / in_sizes[2];
  const int nrows = B * S;

  char* w = (char*)d_ws;
  float* pm   = (float*)w; w += (size_t)nrows * NCHUNK * sizeof(float);
  float* ps   = (float*)w; w += (size_t)nrows * NCHUNK * sizeof(float);
  int*   pidx = (int*)w;   w += (size_t)nrows * NCHUNK * sizeof(int);
  float* psm  = (float*)w; w += (size_t)nrows * NCHUNK * sizeof(float);
  int*   psi  = (int*)w;   w += (size_t)nrows * NCHUNK * sizeof(int);

  int chunk_elems = (V + NCHUNK - 1) / NCHUNK;
  chunk_elems = (chunk_elems + 3) & ~3;  // keep float4 alignment per chunk

  dim3 grid1(NCHUNK, nrows);
  k_stats_partial<<<grid1, dim3(256), 0, stream>>>(logits, V, chunk_elems,
                                                   pm, ps, pidx);
  k_score<<<grid1, dim3(256), 0, stream>>>(
      logits, draft, invq, topk, pm, ps, V, S, chunk_elems, psm, psi);
  k_finalize<<<dim3(B), dim3(64), 0, stream>>>(
      logits, draft, dids, bonus, topk, unif, pm, ps, pidx, psm, psi,
      B, S, V, out);
}